// Round 3
// baseline (3169.494 us; speedup 1.0000x reference)
//
#include <hip/hip_runtime.h>

// Vanilla RNN: B=64, T=512, I=512, H=1024, O=512.
// Phase 1: xin = x @ W_in + b_in  (bf16 MFMA GEMM, store bf16 to ws)
// Phase 2: persistent recurrence, 4 batch-groups x 16 wgs, W_h register-resident.
//          Exchange: tagged bf16 words ((t<<16)|bf16) written with wide plain
//          sc1 (L2-bypass, MALL-coherent) dwordx4 stores; per-producer-WAVE
//          monotonic step flags (vmcnt-ordered) give a cheap 1-dword poll;
//          tags re-validated on the data pass (retry) as correctness backstop.
// Phase 3: out = h_final @ W_out + b_out (fp32 vector).

typedef float f32x4 __attribute__((ext_vector_type(4)));
typedef short bf16x8 __attribute__((ext_vector_type(8)));
typedef short s16x4 __attribute__((ext_vector_type(4)));
typedef unsigned u32;
typedef unsigned u32x4 __attribute__((ext_vector_type(4)));

__device__ __forceinline__ short f2bf(float f) {
  unsigned u = __builtin_bit_cast(unsigned, f);
  u = (u + 0x7FFFu + ((u >> 16) & 1u)) >> 16;   // RNE
  return (short)u;
}
__device__ __forceinline__ float bf2f(short s) {
  unsigned u = ((unsigned)(unsigned short)s) << 16;
  return __builtin_bit_cast(float, u);
}

// ---------------- Phase 1: input projection GEMM --------------------------
__global__ __launch_bounds__(256) void k_inproj(const float* __restrict__ X,
                                                const float* __restrict__ Win,
                                                const float* __restrict__ bin,
                                                short* __restrict__ xin) {
  __shared__ __align__(16) short Al[128][40];
  __shared__ __align__(16) short Bl[128][40];   // stored [n][k]
  __shared__ __align__(16) short Cl[128][64];
  const int m0g = blockIdx.x * 128, n0g = blockIdx.y * 128;
  const int tid = threadIdx.x;
  const int lane = tid & 63, wave = tid >> 6;
  const int wm = (wave & 1) * 64, wn = (wave >> 1) * 64;
  const int l15 = lane & 15, lhi = lane >> 4;

  f32x4 acc[4][4] = {};

  for (int kb = 0; kb < 512; kb += 32) {
    #pragma unroll
    for (int i = 0; i < 4; ++i) {
      int flat = tid + i * 256;
      int row = flat >> 3, k4 = (flat & 7) * 4;
      float4 v = *(const float4*)(X + (size_t)(m0g + row) * 512 + kb + k4);
      s16x4 s; s[0] = f2bf(v.x); s[1] = f2bf(v.y); s[2] = f2bf(v.z); s[3] = f2bf(v.w);
      *(s16x4*)&Al[row][k4] = s;
    }
    #pragma unroll
    for (int i = 0; i < 4; ++i) {
      int flat = tid + i * 256;
      int n = flat & 127, k0 = (flat >> 7) * 4;
      const float* wp = Win + (size_t)(kb + k0) * 1024 + n0g + n;
      s16x4 s;
      s[0] = f2bf(wp[0]); s[1] = f2bf(wp[1024]); s[2] = f2bf(wp[2048]); s[3] = f2bf(wp[3072]);
      *(s16x4*)&Bl[n][k0] = s;
    }
    __syncthreads();
    bf16x8 a[4], b[4];
    #pragma unroll
    for (int mt = 0; mt < 4; ++mt) a[mt] = *(const bf16x8*)&Al[wm + mt * 16 + l15][lhi * 8];
    #pragma unroll
    for (int nt = 0; nt < 4; ++nt) b[nt] = *(const bf16x8*)&Bl[wn + nt * 16 + l15][lhi * 8];
    #pragma unroll
    for (int mt = 0; mt < 4; ++mt)
      #pragma unroll
      for (int nt = 0; nt < 4; ++nt)
        acc[mt][nt] = __builtin_amdgcn_mfma_f32_16x16x32_bf16(a[mt], b[nt], acc[mt][nt], 0, 0, 0);
    __syncthreads();
  }

  float bias[4];
  #pragma unroll
  for (int nt = 0; nt < 4; ++nt) bias[nt] = bin[n0g + wn + nt * 16 + l15];

  #pragma unroll
  for (int h = 0; h < 2; ++h) {
    if ((wave >> 1) == h) {
      #pragma unroll
      for (int mt = 0; mt < 4; ++mt)
        #pragma unroll
        for (int nt = 0; nt < 4; ++nt)
          #pragma unroll
          for (int r = 0; r < 4; ++r) {
            int row = wm + mt * 16 + lhi * 4 + r;
            Cl[row][nt * 16 + l15] = f2bf(acc[mt][nt][r] + bias[nt]);
          }
    }
    __syncthreads();
    {
      int row = tid >> 1, c0 = (tid & 1) * 32;
      const int4* src = (const int4*)&Cl[row][c0];
      int4* dst = (int4*)(xin + (size_t)(m0g + row) * 1024 + n0g + h * 64 + c0);
      dst[0] = src[0]; dst[1] = src[1]; dst[2] = src[2]; dst[3] = src[3];
    }
    __syncthreads();
  }
}

// ---------------- Phase 2: persistent recurrence --------------------------
// 64 wgs x 256 thr. group g = wg>>4 (16 batch rows), cj = wg&15 (64 hidden cols).
// hbuf: u32[2][64 rows][1024 k]; word = (tag<<16)|bf16, tag = consuming step t.
// flags: u32[4 groups][64] = flags[g][cj*4+wave], monotonic "data for step t ready".
__global__ __launch_bounds__(256, 1) void k_recur(const short* __restrict__ xin,
                                                  const float* __restrict__ Wh,
                                                  const float* __restrict__ bh,
                                                  u32* __restrict__ hbuf,
                                                  u32* __restrict__ flags,
                                                  float* __restrict__ hfin) {
  const int wg = blockIdx.x;
  const int g = wg >> 4, cj = wg & 15;
  const int tid = threadIdx.x, lane = tid & 63, wave = tid >> 6;
  const int l15 = lane & 15, lhi = lane >> 4;
  const int colbase = cj << 6, rowbase = g << 4;
  __shared__ __align__(16) float part[2][4][16][68];   // double-buffered K-partials

  // one-time W_h gather -> registers: wave handles K rows [wave*256, +256)
  bf16x8 wf[8][4];
  {
    const float* wp = Wh + (size_t)(wave * 256 + lhi * 8) * 1024 + colbase + l15;
    #pragma unroll
    for (int kt = 0; kt < 8; ++kt)
      #pragma unroll
      for (int nt = 0; nt < 4; ++nt) {
        bf16x8 tmp;
        #pragma unroll
        for (int j = 0; j < 8; ++j)
          tmp[j] = f2bf(wp[(size_t)(kt * 32 + j) * 1024 + nt * 16]);
        wf[kt][nt] = tmp;
      }
  }

  const int erow = tid >> 4, ec0 = (tid & 15) << 2;  // epilogue: row 0..15, 4 cols
  const float4 bh4 = *(const float4*)(bh + colbase + ec0);
  const short* xrow = xin + (size_t)(rowbase + erow) * 512 * 1024 + colbase + ec0;
  const u32* fp = flags + (g << 6) + lane;               // this lane's flag to watch
  u32* myflag = flags + (g << 6) + (cj << 2) + wave;     // this wave's flag

  for (int t = 0; t < 512; ++t) {
    s16x4 xs = *(const s16x4*)(xrow + (size_t)t * 1024);   // plain load (L3-warm)
    f32x4 acc[4] = {};
    if (t > 0) {
      // 1) cheap flag poll: one coalesced sc1 dword per lane per iteration
      for (;;) {
        u32 f;
        asm volatile("global_load_dword %0, %1, off sc1\n\ts_waitcnt vmcnt(0)"
                     : "=v"(f) : "v"(fp) : "memory");
        __builtin_amdgcn_sched_barrier(0);
        if (__all((int)(f >= (u32)t))) break;
      }
      // 2) wide tagged data pass (retry backstop; tags are the ground truth)
      const u32* hs = hbuf + ((t & 1) << 16) + (rowbase + l15) * 1024 + (wave << 8) + lhi * 8;
      u32x4 raw[8][2];
      bool ok;
      do {
        #pragma unroll
        for (int kt = 0; kt < 8; ++kt) {
          asm volatile("global_load_dwordx4 %0, %1, off offset:%c2 sc1"
                       : "=v"(raw[kt][0]) : "v"(hs), "i"(kt * 128) : "memory");
          asm volatile("global_load_dwordx4 %0, %1, off offset:%c2 sc1"
                       : "=v"(raw[kt][1]) : "v"(hs), "i"(kt * 128 + 16) : "memory");
        }
        asm volatile("s_waitcnt vmcnt(0)" ::: "memory");
        __builtin_amdgcn_sched_barrier(0);
        ok = true;
        #pragma unroll
        for (int kt = 0; kt < 8; ++kt)
          #pragma unroll
          for (int q = 0; q < 2; ++q)
            #pragma unroll
            for (int j = 0; j < 4; ++j)
              ok &= ((raw[kt][q][j] >> 16) == (u32)t);
      } while (!__all((int)ok));

      #pragma unroll
      for (int kt = 0; kt < 8; ++kt) {
        bf16x8 a;
        #pragma unroll
        for (int q = 0; q < 2; ++q)
          #pragma unroll
          for (int j = 0; j < 4; ++j)
            a[q * 4 + j] = (short)(raw[kt][q][j] & 0xFFFFu);
        #pragma unroll
        for (int nt = 0; nt < 4; ++nt)
          acc[nt] = __builtin_amdgcn_mfma_f32_16x16x32_bf16(a, wf[kt][nt], acc[nt], 0, 0, 0);
      }
    }
    const int p = t & 1;
    #pragma unroll
    for (int nt = 0; nt < 4; ++nt)
      #pragma unroll
      for (int r = 0; r < 4; ++r)
        part[p][wave][lhi * 4 + r][nt * 16 + l15] = acc[nt][r];
    __syncthreads();   // single barrier per step (partials double-buffered)

    f32x4 p0 = *(const f32x4*)&part[p][0][erow][ec0];
    f32x4 p1 = *(const f32x4*)&part[p][1][erow][ec0];
    f32x4 p2 = *(const f32x4*)&part[p][2][erow][ec0];
    f32x4 p3 = *(const f32x4*)&part[p][3][erow][ec0];
    f32x4 ps = (p0 + p1) + (p2 + p3);
    float h0 = tanhf(ps[0] + bh4.x + bf2f(xs[0]));
    float h1 = tanhf(ps[1] + bh4.y + bf2f(xs[1]));
    float h2 = tanhf(ps[2] + bh4.z + bf2f(xs[2]));
    float h3 = tanhf(ps[3] + bh4.w + bf2f(xs[3]));

    if (t == 511) {
      float4 hf4; hf4.x = h0; hf4.y = h1; hf4.z = h2; hf4.w = h3;
      *(float4*)(hfin + (rowbase + erow) * 1024 + colbase + ec0) = hf4;
    } else {
      const u32 tg = (u32)(t + 1) << 16;
      u32x4 w;
      w[0] = tg | (unsigned short)f2bf(h0);
      w[1] = tg | (unsigned short)f2bf(h1);
      w[2] = tg | (unsigned short)f2bf(h2);
      w[3] = tg | (unsigned short)f2bf(h3);
      u32* dst = hbuf + (((t + 1) & 1) << 16) + (rowbase + erow) * 1024 + colbase + ec0;
      asm volatile("global_store_dwordx4 %0, %1, off sc1" :: "v"(dst), "v"(w) : "memory");
      asm volatile("s_waitcnt vmcnt(0)" ::: "memory");   // wave's sc1 stores at MALL
      if (lane == 0) {
        u32 fv = (u32)(t + 1);
        asm volatile("global_store_dword %0, %1, off sc1" :: "v"(myflag), "v"(fv) : "memory");
      }
    }
  }
}

// ---------------- Phase 3: output projection ------------------------------
__global__ __launch_bounds__(256) void k_out(const float* __restrict__ hfin,
                                             const float* __restrict__ Wout,
                                             const float* __restrict__ bout,
                                             float* __restrict__ out) {
  __shared__ __align__(16) float hrow[1024];
  const int b = blockIdx.x >> 1;
  const int c0 = (blockIdx.x & 1) << 8;
  const int tid = threadIdx.x;
  #pragma unroll
  for (int i = 0; i < 4; ++i) hrow[tid + i * 256] = hfin[b * 1024 + tid + i * 256];
  __syncthreads();
  const int col = c0 + tid;
  const float* wp = Wout + col;
  float a0 = bout[col], a1 = 0, a2 = 0, a3 = 0, a4 = 0, a5 = 0, a6 = 0, a7 = 0;
  #pragma unroll 4
  for (int k = 0; k < 1024; k += 8) {
    a0 += hrow[k + 0] * wp[(size_t)(k + 0) * 512];
    a1 += hrow[k + 1] * wp[(size_t)(k + 1) * 512];
    a2 += hrow[k + 2] * wp[(size_t)(k + 2) * 512];
    a3 += hrow[k + 3] * wp[(size_t)(k + 3) * 512];
    a4 += hrow[k + 4] * wp[(size_t)(k + 4) * 512];
    a5 += hrow[k + 5] * wp[(size_t)(k + 5) * 512];
    a6 += hrow[k + 6] * wp[(size_t)(k + 6) * 512];
    a7 += hrow[k + 7] * wp[(size_t)(k + 7) * 512];
  }
  out[b * 512 + col] = ((a0 + a1) + (a2 + a3)) + ((a4 + a5) + (a6 + a7));
}

// ---------------- launch --------------------------------------------------
extern "C" void kernel_launch(void* const* d_in, const int* in_sizes, int n_in,
                              void* d_out, int out_size, void* d_ws, size_t ws_size,
                              hipStream_t stream) {
  const float* x    = (const float*)d_in[0];
  const float* Win  = (const float*)d_in[1];
  const float* bin  = (const float*)d_in[2];
  const float* Wh   = (const float*)d_in[3];
  const float* bh   = (const float*)d_in[4];
  const float* Wout = (const float*)d_in[5];
  const float* bout = (const float*)d_in[6];

  char* ws = (char*)d_ws;
  short* xin   = (short*)ws;                   // 64*512*1024 bf16 = 67,108,864 B
  u32*   hbuf  = (u32*)(ws + 67108864);        // 2 x 64*1024 u32  = 524,288 B
  u32*   flags = (u32*)(ws + 67633152);        // 4*64 u32 (padded to 1 KiB)
  float* hfin  = (float*)(ws + 67634176);      // 64*1024 f32      = 262,144 B

  hipMemsetAsync(hbuf, 0, 525312, stream);     // clear tags+flags: replay-safe
  hipLaunchKernelGGL(k_inproj, dim3(256, 8), dim3(256), 0, stream, x, Win, bin, xin);
  hipLaunchKernelGGL(k_recur, dim3(64), dim3(256), 0, stream, xin, Wh, bh, hbuf, flags, hfin);
  hipLaunchKernelGGL(k_out, dim3(128), dim3(256), 0, stream, hfin, Wout, bout, (float*)d_out);
}

// Round 4
// 2387.348 us; speedup vs baseline: 1.3276x; 1.3276x over previous
//
#include <hip/hip_runtime.h>

// Vanilla RNN: B=64, T=512, I=512, H=1024, O=512.
// k_prep:   W_h fp32 -> bf16 MFMA-B-fragment layout (per-lane contiguous 16B).
// k_inproj: xin = x @ W_in + b_in (bf16 MFMA GEMM, store bf16 to ws).
// k_recur:  persistent recurrence, 4 batch-groups x 16 wgs (group = wg&3 -> 2 XCDs).
//           W_h fragments loaded ONCE via asm-volatile dwordx4 (un-remat-able,
//           truly register-resident). Exchange: plain bf16 sc1 stores ->
//           vmcnt(0) ack -> per-wave monotonic flag; consumer 1-dword sc1 poll.
// k_out:    out = h_final @ W_out + b_out (fp32 vector).

typedef float f32x4 __attribute__((ext_vector_type(4)));
typedef short bf16x8 __attribute__((ext_vector_type(8)));
typedef short s16x4 __attribute__((ext_vector_type(4)));
typedef unsigned u32;
typedef unsigned u32x2 __attribute__((ext_vector_type(2)));
typedef unsigned u32x4 __attribute__((ext_vector_type(4)));

__device__ __forceinline__ short f2bf(float f) {
  unsigned u = __builtin_bit_cast(unsigned, f);
  u = (u + 0x7FFFu + ((u >> 16) & 1u)) >> 16;   // RNE
  return (short)u;
}
__device__ __forceinline__ float bf2f(short s) {
  unsigned u = ((unsigned)(unsigned short)s) << 16;
  return __builtin_bit_cast(float, u);
}

// ---------------- Phase 0: W_h fragment prep ------------------------------
// wprep element j of bf16x8 at (cj,wslot,kt,nt,lane): Wh[k][n], k = wslot*256 +
// kt*32 + (lane>>4)*8 + j, n = cj*64 + nt*16 + (lane&15). Per-lane contiguous.
__global__ __launch_bounds__(256) void k_prep(const float* __restrict__ Wh,
                                              short* __restrict__ wprep) {
  const int wgid = blockIdx.x;                  // 64 = (cj 16) x (wslot 4)
  const int cj = wgid >> 2, wslot = wgid & 3;
  const int tid = threadIdx.x, lane = tid & 63, sub = tid >> 6;
  const int l15 = lane & 15, lhi = lane >> 4;
  #pragma unroll
  for (int ktl = 0; ktl < 2; ++ktl) {
    int kt = sub * 2 + ktl;
    #pragma unroll
    for (int nt = 0; nt < 4; ++nt) {
      const float* src = Wh + (size_t)(wslot * 256 + kt * 32 + lhi * 8) * 1024
                            + cj * 64 + nt * 16 + l15;
      bf16x8 v;
      #pragma unroll
      for (int j = 0; j < 8; ++j) v[j] = f2bf(src[(size_t)j * 1024]);
      *(bf16x8*)(wprep + ((((size_t)(cj * 4 + wslot) * 8 + kt) * 4 + nt) * 64 + lane) * 8) = v;
    }
  }
}

// ---------------- Phase 1: input projection GEMM --------------------------
__global__ __launch_bounds__(256) void k_inproj(const float* __restrict__ X,
                                                const float* __restrict__ Win,
                                                const float* __restrict__ bin,
                                                short* __restrict__ xin) {
  __shared__ __align__(16) short Al[128][40];
  __shared__ __align__(16) short Bl[128][40];   // stored [n][k]
  __shared__ __align__(16) short Cl[128][64];
  const int m0g = blockIdx.x * 128, n0g = blockIdx.y * 128;
  const int tid = threadIdx.x;
  const int lane = tid & 63, wave = tid >> 6;
  const int wm = (wave & 1) * 64, wn = (wave >> 1) * 64;
  const int l15 = lane & 15, lhi = lane >> 4;

  f32x4 acc[4][4] = {};

  for (int kb = 0; kb < 512; kb += 32) {
    #pragma unroll
    for (int i = 0; i < 4; ++i) {
      int flat = tid + i * 256;
      int row = flat >> 3, k4 = (flat & 7) * 4;
      float4 v = *(const float4*)(X + (size_t)(m0g + row) * 512 + kb + k4);
      s16x4 s; s[0] = f2bf(v.x); s[1] = f2bf(v.y); s[2] = f2bf(v.z); s[3] = f2bf(v.w);
      *(s16x4*)&Al[row][k4] = s;
    }
    #pragma unroll
    for (int i = 0; i < 4; ++i) {
      int flat = tid + i * 256;
      int n = flat & 127, k0 = (flat >> 7) * 4;
      const float* wp = Win + (size_t)(kb + k0) * 1024 + n0g + n;
      s16x4 s;
      s[0] = f2bf(wp[0]); s[1] = f2bf(wp[1024]); s[2] = f2bf(wp[2048]); s[3] = f2bf(wp[3072]);
      *(s16x4*)&Bl[n][k0] = s;
    }
    __syncthreads();
    bf16x8 a[4], b[4];
    #pragma unroll
    for (int mt = 0; mt < 4; ++mt) a[mt] = *(const bf16x8*)&Al[wm + mt * 16 + l15][lhi * 8];
    #pragma unroll
    for (int nt = 0; nt < 4; ++nt) b[nt] = *(const bf16x8*)&Bl[wn + nt * 16 + l15][lhi * 8];
    #pragma unroll
    for (int mt = 0; mt < 4; ++mt)
      #pragma unroll
      for (int nt = 0; nt < 4; ++nt)
        acc[mt][nt] = __builtin_amdgcn_mfma_f32_16x16x32_bf16(a[mt], b[nt], acc[mt][nt], 0, 0, 0);
    __syncthreads();
  }

  float bias[4];
  #pragma unroll
  for (int nt = 0; nt < 4; ++nt) bias[nt] = bin[n0g + wn + nt * 16 + l15];

  #pragma unroll
  for (int h = 0; h < 2; ++h) {
    if ((wave >> 1) == h) {
      #pragma unroll
      for (int mt = 0; mt < 4; ++mt)
        #pragma unroll
        for (int nt = 0; nt < 4; ++nt)
          #pragma unroll
          for (int r = 0; r < 4; ++r) {
            int row = wm + mt * 16 + lhi * 4 + r;
            Cl[row][nt * 16 + l15] = f2bf(acc[mt][nt][r] + bias[nt]);
          }
    }
    __syncthreads();
    {
      int row = tid >> 1, c0 = (tid & 1) * 32;
      const int4* src = (const int4*)&Cl[row][c0];
      int4* dst = (int4*)(xin + (size_t)(m0g + row) * 1024 + n0g + h * 64 + c0);
      dst[0] = src[0]; dst[1] = src[1]; dst[2] = src[2]; dst[3] = src[3];
    }
    __syncthreads();
  }
}

// ---------------- Phase 2: persistent recurrence --------------------------
// 64 wgs x 256 thr. group g = wg&3 (16 batch rows, 2 XCDs), cj = wg>>2 (64 cols).
// hbuf: bf16[2][64 rows][1024 k]. flags: u32[4][64], flag[g][cj*4+wave] = t means
// "h consumed at step t is fully visible at MALL".
__global__ __launch_bounds__(256, 1) void k_recur(const short* __restrict__ xin,
                                                  const short* __restrict__ wprep,
                                                  const float* __restrict__ bh,
                                                  short* __restrict__ hbuf,
                                                  u32* __restrict__ flags,
                                                  float* __restrict__ hfin) {
  const int wg = blockIdx.x;
  const int g = wg & 3, cj = wg >> 2;
  const int tid = threadIdx.x, lane = tid & 63, wave = tid >> 6;
  const int l15 = lane & 15, lhi = lane >> 4;
  const int colbase = cj << 6, rowbase = g << 4;
  __shared__ __align__(16) float part[2][4][16][68];   // double-buffered K-partials

  // W_h fragments -> registers, once. asm volatile => cannot be rematerialized.
  bf16x8 wf[8][4];
  {
    const short* wb = wprep + ((size_t)(cj * 4 + wave) << 14) + lane * 8;
    #pragma unroll
    for (int kt = 0; kt < 8; ++kt)
      #pragma unroll
      for (int nt = 0; nt < 4; ++nt) {
        u32x4 r;
        const short* ap = wb + ((kt * 4 + nt) << 9);
        asm volatile("global_load_dwordx4 %0, %1, off" : "=v"(r) : "v"(ap) : "memory");
        wf[kt][nt] = __builtin_bit_cast(bf16x8, r);
      }
    asm volatile("s_waitcnt vmcnt(0)" ::: "memory");
    __builtin_amdgcn_sched_barrier(0);
  }

  const int erow = tid >> 4, ec0 = (tid & 15) << 2;  // epilogue: row 0..15, 4 cols
  const float4 bh4 = *(const float4*)(bh + colbase + ec0);
  const short* xrow = xin + (size_t)(rowbase + erow) * 512 * 1024 + colbase + ec0;
  const u32* fp = flags + (g << 6) + lane;            // lane watches flag[g][lane]
  u32* myflag = flags + (g << 6) + (cj << 2) + wave;  // this wave's flag
  const short* hsbase = hbuf + (rowbase + l15) * 1024 + (wave << 8) + lhi * 8;
  short* hstore = hbuf + (rowbase + erow) * 1024 + colbase + ec0;

  // ---- t = 0 peel: h = tanh(bh + xin_0), store to buf[1], flag = 1 ----
  {
    s16x4 xs = *(const s16x4*)xrow;
    float h0 = tanhf(bh4.x + bf2f(xs[0]));
    float h1 = tanhf(bh4.y + bf2f(xs[1]));
    float h2 = tanhf(bh4.z + bf2f(xs[2]));
    float h3 = tanhf(bh4.w + bf2f(xs[3]));
    u32x2 w;
    w[0] = ((u32)(unsigned short)f2bf(h1) << 16) | (unsigned short)f2bf(h0);
    w[1] = ((u32)(unsigned short)f2bf(h3) << 16) | (unsigned short)f2bf(h2);
    short* dst = hstore + 65536;
    asm volatile("global_store_dwordx2 %0, %1, off sc1" :: "v"(dst), "v"(w) : "memory");
    asm volatile("s_waitcnt vmcnt(0)" ::: "memory");
    if (lane == 0) {
      u32 fv = 1;
      asm volatile("global_store_dword %0, %1, off sc1" :: "v"(myflag), "v"(fv) : "memory");
    }
  }

  // ---- main loop: t = 1..511, wf used unconditionally ----
  for (int t = 1; t < 512; ++t) {
    s16x4 xs = *(const s16x4*)(xrow + (size_t)t * 1024);
    // 1) poll: one coalesced sc1 dword per lane
    for (;;) {
      u32 f;
      asm volatile("global_load_dword %0, %1, off sc1\n\ts_waitcnt vmcnt(0)"
                   : "=v"(f) : "v"(fp) : "memory");
      __builtin_amdgcn_sched_barrier(0);
      if (__all((int)(f >= (u32)t))) break;
    }
    // 2) wide sc1 data loads (flag-ordered: data acked at MALL before flag)
    const short* hs = hsbase + ((t & 1) << 16);
    u32x4 ar[8];
    #pragma unroll
    for (int kt = 0; kt < 8; ++kt)
      asm volatile("global_load_dwordx4 %0, %1, off offset:%c2 sc1"
                   : "=v"(ar[kt]) : "v"(hs), "i"(kt * 64) : "memory");
    asm volatile("s_waitcnt vmcnt(0)" ::: "memory");
    __builtin_amdgcn_sched_barrier(0);

    f32x4 acc[4] = {};
    #pragma unroll
    for (int kt = 0; kt < 8; ++kt) {
      bf16x8 a = __builtin_bit_cast(bf16x8, ar[kt]);
      #pragma unroll
      for (int nt = 0; nt < 4; ++nt)
        acc[nt] = __builtin_amdgcn_mfma_f32_16x16x32_bf16(a, wf[kt][nt], acc[nt], 0, 0, 0);
    }
    const int p = t & 1;
    #pragma unroll
    for (int nt = 0; nt < 4; ++nt)
      #pragma unroll
      for (int r = 0; r < 4; ++r)
        part[p][wave][lhi * 4 + r][nt * 16 + l15] = acc[nt][r];
    __syncthreads();   // single barrier per step (partials double-buffered)

    f32x4 p0 = *(const f32x4*)&part[p][0][erow][ec0];
    f32x4 p1 = *(const f32x4*)&part[p][1][erow][ec0];
    f32x4 p2 = *(const f32x4*)&part[p][2][erow][ec0];
    f32x4 p3 = *(const f32x4*)&part[p][3][erow][ec0];
    f32x4 ps = (p0 + p1) + (p2 + p3);
    float h0 = tanhf(ps[0] + bh4.x + bf2f(xs[0]));
    float h1 = tanhf(ps[1] + bh4.y + bf2f(xs[1]));
    float h2 = tanhf(ps[2] + bh4.z + bf2f(xs[2]));
    float h3 = tanhf(ps[3] + bh4.w + bf2f(xs[3]));

    if (t < 511) {
      u32x2 w;
      w[0] = ((u32)(unsigned short)f2bf(h1) << 16) | (unsigned short)f2bf(h0);
      w[1] = ((u32)(unsigned short)f2bf(h3) << 16) | (unsigned short)f2bf(h2);
      short* dst = hstore + (((t + 1) & 1) << 16);
      asm volatile("global_store_dwordx2 %0, %1, off sc1" :: "v"(dst), "v"(w) : "memory");
      asm volatile("s_waitcnt vmcnt(0)" ::: "memory");   // data acked at MALL
      if (lane == 0) {
        u32 fv = (u32)(t + 1);
        asm volatile("global_store_dword %0, %1, off sc1" :: "v"(myflag), "v"(fv) : "memory");
      }
    } else {
      float4 hf4; hf4.x = h0; hf4.y = h1; hf4.z = h2; hf4.w = h3;
      *(float4*)(hfin + (rowbase + erow) * 1024 + colbase + ec0) = hf4;
    }
  }
}

// ---------------- Phase 3: output projection ------------------------------
__global__ __launch_bounds__(256) void k_out(const float* __restrict__ hfin,
                                             const float* __restrict__ Wout,
                                             const float* __restrict__ bout,
                                             float* __restrict__ out) {
  __shared__ __align__(16) float hrow[1024];
  const int b = blockIdx.x >> 1;
  const int c0 = (blockIdx.x & 1) << 8;
  const int tid = threadIdx.x;
  #pragma unroll
  for (int i = 0; i < 4; ++i) hrow[tid + i * 256] = hfin[b * 1024 + tid + i * 256];
  __syncthreads();
  const int col = c0 + tid;
  const float* wp = Wout + col;
  float a0 = bout[col], a1 = 0, a2 = 0, a3 = 0, a4 = 0, a5 = 0, a6 = 0, a7 = 0;
  #pragma unroll 4
  for (int k = 0; k < 1024; k += 8) {
    a0 += hrow[k + 0] * wp[(size_t)(k + 0) * 512];
    a1 += hrow[k + 1] * wp[(size_t)(k + 1) * 512];
    a2 += hrow[k + 2] * wp[(size_t)(k + 2) * 512];
    a3 += hrow[k + 3] * wp[(size_t)(k + 3) * 512];
    a4 += hrow[k + 4] * wp[(size_t)(k + 4) * 512];
    a5 += hrow[k + 5] * wp[(size_t)(k + 5) * 512];
    a6 += hrow[k + 6] * wp[(size_t)(k + 6) * 512];
    a7 += hrow[k + 7] * wp[(size_t)(k + 7) * 512];
  }
  out[b * 512 + col] = ((a0 + a1) + (a2 + a3)) + ((a4 + a5) + (a6 + a7));
}

// ---------------- launch --------------------------------------------------
extern "C" void kernel_launch(void* const* d_in, const int* in_sizes, int n_in,
                              void* d_out, int out_size, void* d_ws, size_t ws_size,
                              hipStream_t stream) {
  const float* x    = (const float*)d_in[0];
  const float* Win  = (const float*)d_in[1];
  const float* bin  = (const float*)d_in[2];
  const float* Wh   = (const float*)d_in[3];
  const float* bh   = (const float*)d_in[4];
  const float* Wout = (const float*)d_in[5];
  const float* bout = (const float*)d_in[6];

  char* ws = (char*)d_ws;
  short* xin   = (short*)ws;                   // 64*512*1024 bf16 = 67,108,864 B
  short* wprep = (short*)(ws + 67108864);      // 2 MB bf16 fragments
  short* hbuf  = (short*)(ws + 69206016);      // 2 x 64*1024 bf16 = 262,144 B
  u32*   flags = (u32*)(ws + 69468160);        // 4*64 u32, padded to 1 KiB
  float* hfin  = (float*)(ws + 69469184);      // 64*1024 f32      = 262,144 B

  hipMemsetAsync(flags, 0, 1024, stream);      // replay-deterministic
  hipLaunchKernelGGL(k_prep, dim3(64), dim3(256), 0, stream, Wh, wprep);
  hipLaunchKernelGGL(k_inproj, dim3(256, 8), dim3(256), 0, stream, x, Win, bin, xin);
  hipLaunchKernelGGL(k_recur, dim3(64), dim3(256), 0, stream, xin, wprep, bh, hbuf, flags, hfin);
  hipLaunchKernelGGL(k_out, dim3(128), dim3(256), 0, stream, hfin, Wout, bout, (float*)d_out);
}

// Round 6
// 2255.051 us; speedup vs baseline: 1.4055x; 1.0587x over previous
//
#include <hip/hip_runtime.h>

// Vanilla RNN: B=64, T=512, I=512, H=1024, O=512.
// k_prep:   W_h fp32 -> bf16 MFMA-B-fragment layout (per-lane contiguous 16B).
// k_inproj: xin = x @ W_in + b_in (bf16 MFMA GEMM, store bf16 to ws).
// k_recur:  persistent recurrence, 4 batch-groups x 16 wgs, W_h register/AGPR-
//           resident (asm-volatile one-time loads). h exchange: SELF-SYNCING
//           tagged words ((t<<16)|bf16) via sc1 (MALL-coherent) dwordx4 stores,
//           fire-and-forget; consumer poll-loads its MFMA fragments directly
//           and retries until all 32 tags == t. No fences, no flags, no acks.
// k_out:    out = h_final @ W_out + b_out (fp32 vector).

typedef float f32x4 __attribute__((ext_vector_type(4)));
typedef short bf16x8 __attribute__((ext_vector_type(8)));
typedef short s16x4 __attribute__((ext_vector_type(4)));
typedef unsigned u32;
typedef unsigned u32x4 __attribute__((ext_vector_type(4)));

__device__ __forceinline__ short f2bf(float f) {
  unsigned u = __builtin_bit_cast(unsigned, f);
  u = (u + 0x7FFFu + ((u >> 16) & 1u)) >> 16;   // RNE
  return (short)u;
}
__device__ __forceinline__ float bf2f(short s) {
  unsigned u = ((unsigned)(unsigned short)s) << 16;
  return __builtin_bit_cast(float, u);
}

// ---------------- Phase 0: W_h fragment prep ------------------------------
// wprep element j of bf16x8 at (cj,wslot,kt,nt,lane): Wh[k][n], k = wslot*256 +
// kt*32 + (lane>>4)*8 + j, n = cj*64 + nt*16 + (lane&15). Per-lane contiguous.
__global__ __launch_bounds__(256) void k_prep(const float* __restrict__ Wh,
                                              short* __restrict__ wprep) {
  const int wgid = blockIdx.x;                  // 64 = (cj 16) x (wslot 4)
  const int cj = wgid >> 2, wslot = wgid & 3;
  const int tid = threadIdx.x, lane = tid & 63, sub = tid >> 6;
  const int l15 = lane & 15, lhi = lane >> 4;
  #pragma unroll
  for (int ktl = 0; ktl < 2; ++ktl) {
    int kt = sub * 2 + ktl;
    #pragma unroll
    for (int nt = 0; nt < 4; ++nt) {
      const float* src = Wh + (size_t)(wslot * 256 + kt * 32 + lhi * 8) * 1024
                            + cj * 64 + nt * 16 + l15;
      bf16x8 v;
      #pragma unroll
      for (int j = 0; j < 8; ++j) v[j] = f2bf(src[(size_t)j * 1024]);
      *(bf16x8*)(wprep + ((((size_t)(cj * 4 + wslot) * 8 + kt) * 4 + nt) * 64 + lane) * 8) = v;
    }
  }
}

// ---------------- Phase 1: input projection GEMM --------------------------
__global__ __launch_bounds__(256) void k_inproj(const float* __restrict__ X,
                                                const float* __restrict__ Win,
                                                const float* __restrict__ bin,
                                                short* __restrict__ xin) {
  __shared__ __align__(16) short Al[128][40];
  __shared__ __align__(16) short Bl[128][40];   // stored [n][k]
  __shared__ __align__(16) short Cl[128][64];
  const int m0g = blockIdx.x * 128, n0g = blockIdx.y * 128;
  const int tid = threadIdx.x;
  const int lane = tid & 63, wave = tid >> 6;
  const int wm = (wave & 1) * 64, wn = (wave >> 1) * 64;
  const int l15 = lane & 15, lhi = lane >> 4;

  f32x4 acc[4][4] = {};

  for (int kb = 0; kb < 512; kb += 32) {
    #pragma unroll
    for (int i = 0; i < 4; ++i) {
      int flat = tid + i * 256;
      int row = flat >> 3, k4 = (flat & 7) * 4;
      float4 v = *(const float4*)(X + (size_t)(m0g + row) * 512 + kb + k4);
      s16x4 s; s[0] = f2bf(v.x); s[1] = f2bf(v.y); s[2] = f2bf(v.z); s[3] = f2bf(v.w);
      *(s16x4*)&Al[row][k4] = s;
    }
    #pragma unroll
    for (int i = 0; i < 4; ++i) {
      int flat = tid + i * 256;
      int n = flat & 127, k0 = (flat >> 7) * 4;
      const float* wp = Win + (size_t)(kb + k0) * 1024 + n0g + n;
      s16x4 s;
      s[0] = f2bf(wp[0]); s[1] = f2bf(wp[1024]); s[2] = f2bf(wp[2048]); s[3] = f2bf(wp[3072]);
      *(s16x4*)&Bl[n][k0] = s;
    }
    __syncthreads();
    bf16x8 a[4], b[4];
    #pragma unroll
    for (int mt = 0; mt < 4; ++mt) a[mt] = *(const bf16x8*)&Al[wm + mt * 16 + l15][lhi * 8];
    #pragma unroll
    for (int nt = 0; nt < 4; ++nt) b[nt] = *(const bf16x8*)&Bl[wn + nt * 16 + l15][lhi * 8];
    #pragma unroll
    for (int mt = 0; mt < 4; ++mt)
      #pragma unroll
      for (int nt = 0; nt < 4; ++nt)
        acc[mt][nt] = __builtin_amdgcn_mfma_f32_16x16x32_bf16(a[mt], b[nt], acc[mt][nt], 0, 0, 0);
    __syncthreads();
  }

  float bias[4];
  #pragma unroll
  for (int nt = 0; nt < 4; ++nt) bias[nt] = bin[n0g + wn + nt * 16 + l15];

  #pragma unroll
  for (int h = 0; h < 2; ++h) {
    if ((wave >> 1) == h) {
      #pragma unroll
      for (int mt = 0; mt < 4; ++mt)
        #pragma unroll
        for (int nt = 0; nt < 4; ++nt)
          #pragma unroll
          for (int r = 0; r < 4; ++r) {
            int row = wm + mt * 16 + lhi * 4 + r;
            Cl[row][nt * 16 + l15] = f2bf(acc[mt][nt][r] + bias[nt]);
          }
    }
    __syncthreads();
    {
      int row = tid >> 1, c0 = (tid & 1) * 32;
      const int4* src = (const int4*)&Cl[row][c0];
      int4* dst = (int4*)(xin + (size_t)(m0g + row) * 1024 + n0g + h * 64 + c0);
      dst[0] = src[0]; dst[1] = src[1]; dst[2] = src[2]; dst[3] = src[3];
    }
    __syncthreads();
  }
}

// ---------------- Phase 2: persistent recurrence --------------------------
// 64 wgs x 256 thr. group g = wg&3 (16 batch rows), cj = wg>>2 (64 cols).
// hbuf: u32[2][64 rows][1024 k]; word = (tag<<16)|bf16, tag = consuming step t
// (h produced at end of step t-1 carries tag t). Parity double-buffer; a slot
// is only overwritten at t+2, after every consumer finished reading t (r2-proven
// dataflow invariant). Full memset per call kills cross-replay tag aliasing.
__global__ __launch_bounds__(256, 1) void k_recur(const short* __restrict__ xin,
                                                  const short* __restrict__ wprep,
                                                  const float* __restrict__ bh,
                                                  u32* __restrict__ hbuf,
                                                  float* __restrict__ hfin) {
  const int wg = blockIdx.x;
  const int g = wg & 3, cj = wg >> 2;
  const int tid = threadIdx.x, lane = tid & 63, wave = tid >> 6;
  const int l15 = lane & 15, lhi = lane >> 4;
  const int colbase = cj << 6, rowbase = g << 4;
  __shared__ __align__(16) float part[2][4][16][68];   // double-buffered K-partials

  // W_h fragments -> registers/AGPRs, once. asm volatile => un-rematerializable.
  bf16x8 wf[8][4];
  {
    const short* wb = wprep + ((size_t)(cj * 4 + wave) << 14) + lane * 8;
    #pragma unroll
    for (int kt = 0; kt < 8; ++kt)
      #pragma unroll
      for (int nt = 0; nt < 4; ++nt) {
        u32x4 r;
        const short* ap = wb + ((kt * 4 + nt) << 9);
        asm volatile("global_load_dwordx4 %0, %1, off" : "=v"(r) : "v"(ap) : "memory");
        wf[kt][nt] = __builtin_bit_cast(bf16x8, r);
      }
    asm volatile("s_waitcnt vmcnt(0)" ::: "memory");
    __builtin_amdgcn_sched_barrier(0);
  }

  const int erow = tid >> 4, ec0 = (tid & 15) << 2;  // epilogue: row 0..15, 4 cols
  const float4 bh4 = *(const float4*)(bh + colbase + ec0);
  const short* xrow = xin + (size_t)(rowbase + erow) * 512 * 1024 + colbase + ec0;
  const u32* hsbase = hbuf + (rowbase + l15) * 1024 + (wave << 8) + lhi * 8;
  u32* hstore = hbuf + (rowbase + erow) * 1024 + colbase + ec0;

  // ---- t = 0 peel: h = tanh(bh + xin_0), tagged store to buf[1], tag 1 ----
  {
    s16x4 xs = *(const s16x4*)xrow;
    float h0 = tanhf(bh4.x + bf2f(xs[0]));
    float h1 = tanhf(bh4.y + bf2f(xs[1]));
    float h2 = tanhf(bh4.z + bf2f(xs[2]));
    float h3 = tanhf(bh4.w + bf2f(xs[3]));
    u32x4 wv;
    wv[0] = (1u << 16) | (unsigned short)f2bf(h0);
    wv[1] = (1u << 16) | (unsigned short)f2bf(h1);
    wv[2] = (1u << 16) | (unsigned short)f2bf(h2);
    wv[3] = (1u << 16) | (unsigned short)f2bf(h3);
    u32* dst = hstore + 65536;
    asm volatile("global_store_dwordx4 %0, %1, off sc1" :: "v"(dst), "v"(wv) : "memory");
  }

  // ---- main loop: t = 1..511, wf used unconditionally ----
  for (int t = 1; t < 512; ++t) {
    s16x4 xs = *(const s16x4*)(xrow + (size_t)t * 1024);
    // poll-load the wave's A-fragments; retry until all 32 tags == t.
    const u32* hs = hsbase + ((t & 1) << 16);
    u32x4 r0[8], r1[8];
    bool ok;
    do {
      #pragma unroll
      for (int kt = 0; kt < 8; ++kt) {
        asm volatile("global_load_dwordx4 %0, %1, off offset:%c2 sc1"
                     : "=v"(r0[kt]) : "v"(hs), "i"(kt * 128) : "memory");
        asm volatile("global_load_dwordx4 %0, %1, off offset:%c2 sc1"
                     : "=v"(r1[kt]) : "v"(hs), "i"(kt * 128 + 16) : "memory");
      }
      asm volatile("s_waitcnt vmcnt(0)" ::: "memory");
      __builtin_amdgcn_sched_barrier(0);         // rule #18: pin checks after wait
      ok = true;
      #pragma unroll
      for (int kt = 0; kt < 8; ++kt)
        #pragma unroll
        for (int j = 0; j < 4; ++j) {
          ok &= ((r0[kt][j] >> 16) == (u32)t);
          ok &= ((r1[kt][j] >> 16) == (u32)t);
        }
    } while (!__all((int)ok));

    f32x4 acc[4] = {};
    #pragma unroll
    for (int kt = 0; kt < 8; ++kt) {
      bf16x8 a;
      #pragma unroll
      for (int j = 0; j < 4; ++j) {
        a[j]     = (short)(r0[kt][j] & 0xFFFFu);
        a[4 + j] = (short)(r1[kt][j] & 0xFFFFu);
      }
      #pragma unroll
      for (int nt = 0; nt < 4; ++nt)
        acc[nt] = __builtin_amdgcn_mfma_f32_16x16x32_bf16(a, wf[kt][nt], acc[nt], 0, 0, 0);
    }
    const int p = t & 1;
    #pragma unroll
    for (int nt = 0; nt < 4; ++nt)
      #pragma unroll
      for (int r = 0; r < 4; ++r)
        part[p][wave][lhi * 4 + r][nt * 16 + l15] = acc[nt][r];
    __syncthreads();   // single barrier per step (partials double-buffered)

    f32x4 p0 = *(const f32x4*)&part[p][0][erow][ec0];
    f32x4 p1 = *(const f32x4*)&part[p][1][erow][ec0];
    f32x4 p2 = *(const f32x4*)&part[p][2][erow][ec0];
    f32x4 p3 = *(const f32x4*)&part[p][3][erow][ec0];
    f32x4 ps = (p0 + p1) + (p2 + p3);
    float h0 = tanhf(ps[0] + bh4.x + bf2f(xs[0]));
    float h1 = tanhf(ps[1] + bh4.y + bf2f(xs[1]));
    float h2 = tanhf(ps[2] + bh4.z + bf2f(xs[2]));
    float h3 = tanhf(ps[3] + bh4.w + bf2f(xs[3]));

    if (t < 511) {
      const u32 tg = (u32)(t + 1) << 16;
      u32x4 wv;
      wv[0] = tg | (unsigned short)f2bf(h0);
      wv[1] = tg | (unsigned short)f2bf(h1);
      wv[2] = tg | (unsigned short)f2bf(h2);
      wv[3] = tg | (unsigned short)f2bf(h3);
      u32* dst = hstore + (((t + 1) & 1) << 16);
      asm volatile("global_store_dwordx4 %0, %1, off sc1" :: "v"(dst), "v"(wv) : "memory");
      // fire-and-forget: no ack, no flag — consumers validate via tags.
    } else {
      float4 hf4; hf4.x = h0; hf4.y = h1; hf4.z = h2; hf4.w = h3;
      *(float4*)(hfin + (rowbase + erow) * 1024 + colbase + ec0) = hf4;
    }
  }
}

// ---------------- Phase 3: output projection ------------------------------
__global__ __launch_bounds__(256) void k_out(const float* __restrict__ hfin,
                                             const float* __restrict__ Wout,
                                             const float* __restrict__ bout,
                                             float* __restrict__ out) {
  __shared__ __align__(16) float hrow[1024];
  const int b = blockIdx.x >> 1;
  const int c0 = (blockIdx.x & 1) << 8;
  const int tid = threadIdx.x;
  #pragma unroll
  for (int i = 0; i < 4; ++i) hrow[tid + i * 256] = hfin[b * 1024 + tid + i * 256];
  __syncthreads();
  const int col = c0 + tid;
  const float* wp = Wout + col;
  float a0 = bout[col], a1 = 0, a2 = 0, a3 = 0, a4 = 0, a5 = 0, a6 = 0, a7 = 0;
  #pragma unroll 4
  for (int k = 0; k < 1024; k += 8) {
    a0 += hrow[k + 0] * wp[(size_t)(k + 0) * 512];
    a1 += hrow[k + 1] * wp[(size_t)(k + 1) * 512];
    a2 += hrow[k + 2] * wp[(size_t)(k + 2) * 512];
    a3 += hrow[k + 3] * wp[(size_t)(k + 3) * 512];
    a4 += hrow[k + 4] * wp[(size_t)(k + 4) * 512];
    a5 += hrow[k + 5] * wp[(size_t)(k + 5) * 512];
    a6 += hrow[k + 6] * wp[(size_t)(k + 6) * 512];
    a7 += hrow[k + 7] * wp[(size_t)(k + 7) * 512];
  }
  out[b * 512 + col] = ((a0 + a1) + (a2 + a3)) + ((a4 + a5) + (a6 + a7));
}

// ---------------- launch --------------------------------------------------
extern "C" void kernel_launch(void* const* d_in, const int* in_sizes, int n_in,
                              void* d_out, int out_size, void* d_ws, size_t ws_size,
                              hipStream_t stream) {
  const float* x    = (const float*)d_in[0];
  const float* Win  = (const float*)d_in[1];
  const float* bin  = (const float*)d_in[2];
  const float* Wh   = (const float*)d_in[3];
  const float* bh   = (const float*)d_in[4];
  const float* Wout = (const float*)d_in[5];
  const float* bout = (const float*)d_in[6];

  char* ws = (char*)d_ws;
  short* xin   = (short*)ws;                   // 64*512*1024 bf16 = 67,108,864 B
  short* wprep = (short*)(ws + 67108864);      // 2 MB bf16 fragments
  u32*   hbuf  = (u32*)(ws + 69206016);        // 2 x 64*1024 u32  = 524,288 B
  float* hfin  = (float*)(ws + 69730304);      // 64*1024 f32      = 262,144 B

  hipMemsetAsync(hbuf, 0, 524288, stream);     // clear all tags: replay-safe
  hipLaunchKernelGGL(k_prep, dim3(64), dim3(256), 0, stream, Wh, wprep);
  hipLaunchKernelGGL(k_inproj, dim3(256, 8), dim3(256), 0, stream, x, Win, bin, xin);
  hipLaunchKernelGGL(k_recur, dim3(64), dim3(256), 0, stream, xin, wprep, bh, hbuf, hfin);
  hipLaunchKernelGGL(k_out, dim3(128), dim3(256), 0, stream, hfin, Wout, bout, (float*)d_out);
}

// Round 8
// 1431.362 us; speedup vs baseline: 2.2143x; 1.5755x over previous
//
#include <hip/hip_runtime.h>

// Vanilla RNN: B=64, T=512, I=512, H=1024, O=512.
// k_prep:   W_h fp32 -> bf16 MFMA-B-fragment layout (per-lane contiguous 16B).
// k_inproj: xin = x @ W_in + b_in, stored bf16 re-laid-out as [g][t][16r][1024].
// k_recur:  persistent recurrence, 4 groups x 16 wgs, W_h register-resident.
//           h exchange in CONSUMER-FRAGMENT LAYOUT: producer scatters 8B stores
//           into per-(kslice,kt) 1KB blocks; consumer does 8 coalesced 1KB
//           dwordx4 sc1 loads that ARE the MFMA A-fragments. Flag protocol:
//           data sc1 -> vmcnt ack -> barrier -> per-wg flag sc1; consumer polls
//           its 4 producer flags with one coalesced dword.
// k_out:    out = h_final @ W_out + b_out (fp32 vector).

typedef float f32x4 __attribute__((ext_vector_type(4)));
typedef short bf16x8 __attribute__((ext_vector_type(8)));
typedef short s16x4 __attribute__((ext_vector_type(4)));
typedef unsigned u32;
typedef unsigned u32x2 __attribute__((ext_vector_type(2)));
typedef unsigned u32x4 __attribute__((ext_vector_type(4)));

__device__ __forceinline__ short f2bf(float f) {
  unsigned u = __builtin_bit_cast(unsigned, f);
  u = (u + 0x7FFFu + ((u >> 16) & 1u)) >> 16;   // RNE
  return (short)u;
}
__device__ __forceinline__ float bf2f(short s) {
  unsigned u = ((unsigned)(unsigned short)s) << 16;
  return __builtin_bit_cast(float, u);
}

// ---------------- Phase 0: W_h fragment prep ------------------------------
__global__ __launch_bounds__(256) void k_prep(const float* __restrict__ Wh,
                                              short* __restrict__ wprep) {
  const int wgid = blockIdx.x;                  // 64 = (cj 16) x (wslot 4)
  const int cj = wgid >> 2, wslot = wgid & 3;
  const int tid = threadIdx.x, lane = tid & 63, sub = tid >> 6;
  const int l15 = lane & 15, lhi = lane >> 4;
  #pragma unroll
  for (int ktl = 0; ktl < 2; ++ktl) {
    int kt = sub * 2 + ktl;
    #pragma unroll
    for (int nt = 0; nt < 4; ++nt) {
      const float* src = Wh + (size_t)(wslot * 256 + kt * 32 + lhi * 8) * 1024
                            + cj * 64 + nt * 16 + l15;
      bf16x8 v;
      #pragma unroll
      for (int j = 0; j < 8; ++j) v[j] = f2bf(src[(size_t)j * 1024]);
      *(bf16x8*)(wprep + ((((size_t)(cj * 4 + wslot) * 8 + kt) * 4 + nt) * 64 + lane) * 8) = v;
    }
  }
}

// ---------------- Phase 1: input projection GEMM --------------------------
// Output layout: xin[((g*512 + t)*16 + r)*1024 + n], g=b>>4, r=b&15, b=m>>9.
__global__ __launch_bounds__(256) void k_inproj(const float* __restrict__ X,
                                                const float* __restrict__ Win,
                                                const float* __restrict__ bin,
                                                short* __restrict__ xin) {
  __shared__ __align__(16) short Al[128][40];
  __shared__ __align__(16) short Bl[128][40];   // stored [n][k]
  __shared__ __align__(16) short Cl[128][64];
  const int m0g = blockIdx.x * 128, n0g = blockIdx.y * 128;
  const int tid = threadIdx.x;
  const int lane = tid & 63, wave = tid >> 6;
  const int wm = (wave & 1) * 64, wn = (wave >> 1) * 64;
  const int l15 = lane & 15, lhi = lane >> 4;

  f32x4 acc[4][4] = {};

  for (int kb = 0; kb < 512; kb += 32) {
    #pragma unroll
    for (int i = 0; i < 4; ++i) {
      int flat = tid + i * 256;
      int row = flat >> 3, k4 = (flat & 7) * 4;
      float4 v = *(const float4*)(X + (size_t)(m0g + row) * 512 + kb + k4);
      s16x4 s; s[0] = f2bf(v.x); s[1] = f2bf(v.y); s[2] = f2bf(v.z); s[3] = f2bf(v.w);
      *(s16x4*)&Al[row][k4] = s;
    }
    #pragma unroll
    for (int i = 0; i < 4; ++i) {
      int flat = tid + i * 256;
      int n = flat & 127, k0 = (flat >> 7) * 4;
      const float* wp = Win + (size_t)(kb + k0) * 1024 + n0g + n;
      s16x4 s;
      s[0] = f2bf(wp[0]); s[1] = f2bf(wp[1024]); s[2] = f2bf(wp[2048]); s[3] = f2bf(wp[3072]);
      *(s16x4*)&Bl[n][k0] = s;
    }
    __syncthreads();
    bf16x8 a[4], b[4];
    #pragma unroll
    for (int mt = 0; mt < 4; ++mt) a[mt] = *(const bf16x8*)&Al[wm + mt * 16 + l15][lhi * 8];
    #pragma unroll
    for (int nt = 0; nt < 4; ++nt) b[nt] = *(const bf16x8*)&Bl[wn + nt * 16 + l15][lhi * 8];
    #pragma unroll
    for (int mt = 0; mt < 4; ++mt)
      #pragma unroll
      for (int nt = 0; nt < 4; ++nt)
        acc[mt][nt] = __builtin_amdgcn_mfma_f32_16x16x32_bf16(a[mt], b[nt], acc[mt][nt], 0, 0, 0);
    __syncthreads();
  }

  float bias[4];
  #pragma unroll
  for (int nt = 0; nt < 4; ++nt) bias[nt] = bin[n0g + wn + nt * 16 + l15];

  const size_t gbase = ((size_t)(m0g >> 13) * 512 + (m0g & 511)) * 16 + ((m0g >> 9) & 15);
  #pragma unroll
  for (int h = 0; h < 2; ++h) {
    if ((wave >> 1) == h) {
      #pragma unroll
      for (int mt = 0; mt < 4; ++mt)
        #pragma unroll
        for (int nt = 0; nt < 4; ++nt)
          #pragma unroll
          for (int r = 0; r < 4; ++r) {
            int row = wm + mt * 16 + lhi * 4 + r;
            Cl[row][nt * 16 + l15] = f2bf(acc[mt][nt][r] + bias[nt]);
          }
    }
    __syncthreads();
    {
      int row = tid >> 1, c0 = (tid & 1) * 32;
      const int4* src = (const int4*)&Cl[row][c0];
      int4* dst = (int4*)(xin + (gbase + (size_t)row * 16) * 1024 + n0g + h * 64 + c0);
      dst[0] = src[0]; dst[1] = src[1]; dst[2] = src[2]; dst[3] = src[3];
    }
    __syncthreads();
  }
}

// ---------------- Phase 2: persistent recurrence --------------------------
// hfrag: bf16[2 parity][4 g][4 kslice][8 kt][64 lane][8] = 256 KB. Block
// (p,g,w,kt) holds A-frag of h rows 0..15, k = w*256+kt*32..+32 in lane order.
// flags: u32[4][16], flag[g][j] = t means "wg j's h for consuming step t is at
// the MALL". Consumer wave w needs only producers j = 4w..4w+3.
__global__ __launch_bounds__(256, 1) void k_recur(const short* __restrict__ xin,
                                                  const short* __restrict__ wprep,
                                                  const float* __restrict__ bh,
                                                  short* __restrict__ hfrag,
                                                  u32* __restrict__ flags,
                                                  float* __restrict__ hfin) {
  const int wg = blockIdx.x;
  const int g = wg & 3, cj = wg >> 2;
  const int tid = threadIdx.x, lane = tid & 63, wave = tid >> 6;
  const int l15 = lane & 15, lhi = lane >> 4;
  const int colbase = cj << 6, rowbase = g << 4;
  __shared__ __align__(16) float part[4][16][68];

  // W_h fragments -> registers/AGPRs, once (asm volatile: un-rematerializable).
  bf16x8 wf[8][4];
  {
    const short* wb = wprep + ((size_t)(cj * 4 + wave) << 14) + lane * 8;
    #pragma unroll
    for (int kt = 0; kt < 8; ++kt)
      #pragma unroll
      for (int nt = 0; nt < 4; ++nt) {
        u32x4 r;
        const short* ap = wb + ((kt * 4 + nt) << 9);
        asm volatile("global_load_dwordx4 %0, %1, off" : "=v"(r) : "v"(ap) : "memory");
        wf[kt][nt] = __builtin_bit_cast(bf16x8, r);
      }
    asm volatile("s_waitcnt vmcnt(0)" ::: "memory");
    __builtin_amdgcn_sched_barrier(0);
  }

  const int erow = tid >> 4, ec0 = (tid & 15) << 2;  // epilogue: row, 4 cols
  const int n0 = colbase + ec0;                      // global column of quad
  const float4 bh4 = *(const float4*)(bh + n0);
  const short* xbase = xin + (size_t)g * 512 * 16384 + erow * 1024 + n0;
  const u32* fp = flags + (g << 4) + (wave << 2) + (lane & 3);  // 4 producer flags
  u32* myflag = flags + (g << 4) + cj;
  // consumer read bases (parity 0): kt 0..3 from hrd0, kt 4..7 from hrd1
  // (13-bit signed imm offset caps at 4095 -> split 8KB block across 2 bases)
  const short* hrd0 = hfrag + ((g << 2) + wave) * 4096 + lane * 8;
  const short* hrd1 = hrd0 + 2048;                   // +4096 bytes
  // producer store offset (parity 0) for this thread's column quad
  short* hwr = hfrag + (g << 14) + ((n0 >> 8) << 12) + (((n0 >> 5) & 7) << 9)
                     + ((((n0 & 31) >> 3) << 4) + erow) * 8 + (n0 & 7);

  // ---- t = 0 peel: h = tanh(bh + xin_0) -> fragment store (parity 1), flag 1
  {
    s16x4 xs = *(const s16x4*)xbase;
    float h0 = tanhf(bh4.x + bf2f(xs[0]));
    float h1 = tanhf(bh4.y + bf2f(xs[1]));
    float h2 = tanhf(bh4.z + bf2f(xs[2]));
    float h3 = tanhf(bh4.w + bf2f(xs[3]));
    u32x2 wv;
    wv[0] = ((u32)(unsigned short)f2bf(h1) << 16) | (unsigned short)f2bf(h0);
    wv[1] = ((u32)(unsigned short)f2bf(h3) << 16) | (unsigned short)f2bf(h2);
    short* dst = hwr + 65536;
    asm volatile("global_store_dwordx2 %0, %1, off sc1" :: "v"(dst), "v"(wv) : "memory");
    asm volatile("s_waitcnt vmcnt(0)" ::: "memory");
    __syncthreads();                         // all 4 waves' stores acked
    if (tid == 0) {
      u32 fv = 1;
      asm volatile("global_store_dword %0, %1, off sc1" :: "v"(myflag), "v"(fv) : "memory");
    }
  }

  // ---- main loop: t = 1..511 ----
  for (int t = 1; t < 512; ++t) {
    s16x4 xs = *(const s16x4*)(xbase + (size_t)t * 16384);
    // 1) poll the 4 producer flags (one coalesced dword per lane)
    for (;;) {
      u32 f;
      asm volatile("global_load_dword %0, %1, off sc1\n\ts_waitcnt vmcnt(0)"
                   : "=v"(f) : "v"(fp) : "memory");
      __builtin_amdgcn_sched_barrier(0);
      if (__all((int)(f >= (u32)t))) break;
    }
    // 2) 8 coalesced 1KB fragment loads — these ARE the MFMA A-operands
    const int poff = (t & 1) << 16;
    const short* hs0 = hrd0 + poff;
    const short* hs1 = hrd1 + poff;
    u32x4 ar[8];
    #pragma unroll
    for (int kt = 0; kt < 4; ++kt) {
      asm volatile("global_load_dwordx4 %0, %1, off offset:%c2 sc1"
                   : "=v"(ar[kt]) : "v"(hs0), "i"(kt * 1024) : "memory");
      asm volatile("global_load_dwordx4 %0, %1, off offset:%c2 sc1"
                   : "=v"(ar[kt + 4]) : "v"(hs1), "i"(kt * 1024) : "memory");
    }
    asm volatile("s_waitcnt vmcnt(0)" ::: "memory");
    __builtin_amdgcn_sched_barrier(0);

    f32x4 acc[4] = {};
    #pragma unroll
    for (int kt = 0; kt < 8; ++kt) {
      bf16x8 a = __builtin_bit_cast(bf16x8, ar[kt]);
      #pragma unroll
      for (int nt = 0; nt < 4; ++nt)
        acc[nt] = __builtin_amdgcn_mfma_f32_16x16x32_bf16(a, wf[kt][nt], acc[nt], 0, 0, 0);
    }
    #pragma unroll
    for (int nt = 0; nt < 4; ++nt)
      #pragma unroll
      for (int r = 0; r < 4; ++r)
        part[wave][lhi * 4 + r][nt * 16 + l15] = acc[nt][r];
    __syncthreads();

    f32x4 p0 = *(const f32x4*)&part[0][erow][ec0];
    f32x4 p1 = *(const f32x4*)&part[1][erow][ec0];
    f32x4 p2 = *(const f32x4*)&part[2][erow][ec0];
    f32x4 p3 = *(const f32x4*)&part[3][erow][ec0];
    f32x4 ps = (p0 + p1) + (p2 + p3);
    float h0 = tanhf(ps[0] + bh4.x + bf2f(xs[0]));
    float h1 = tanhf(ps[1] + bh4.y + bf2f(xs[1]));
    float h2 = tanhf(ps[2] + bh4.z + bf2f(xs[2]));
    float h3 = tanhf(ps[3] + bh4.w + bf2f(xs[3]));

    if (t < 511) {
      u32x2 wv;
      wv[0] = ((u32)(unsigned short)f2bf(h1) << 16) | (unsigned short)f2bf(h0);
      wv[1] = ((u32)(unsigned short)f2bf(h3) << 16) | (unsigned short)f2bf(h2);
      short* dst = hwr + (((t + 1) & 1) << 16);
      asm volatile("global_store_dwordx2 %0, %1, off sc1" :: "v"(dst), "v"(wv) : "memory");
      asm volatile("s_waitcnt vmcnt(0)" ::: "memory");   // this wave's data acked
      __syncthreads();                                   // whole wg's data acked
      if (tid == 0) {
        u32 fv = (u32)(t + 1);
        asm volatile("global_store_dword %0, %1, off sc1" :: "v"(myflag), "v"(fv) : "memory");
      }
    } else {
      float4 hf4; hf4.x = h0; hf4.y = h1; hf4.z = h2; hf4.w = h3;
      *(float4*)(hfin + (rowbase + erow) * 1024 + n0) = hf4;
      __syncthreads();
    }
  }
}

// ---------------- Phase 3: output projection ------------------------------
__global__ __launch_bounds__(256) void k_out(const float* __restrict__ hfin,
                                             const float* __restrict__ Wout,
                                             const float* __restrict__ bout,
                                             float* __restrict__ out) {
  __shared__ __align__(16) float hrow[1024];
  const int b = blockIdx.x >> 1;
  const int c0 = (blockIdx.x & 1) << 8;
  const int tid = threadIdx.x;
  #pragma unroll
  for (int i = 0; i < 4; ++i) hrow[tid + i * 256] = hfin[b * 1024 + tid + i * 256];
  __syncthreads();
  const int col = c0 + tid;
  const float* wp = Wout + col;
  float a0 = bout[col], a1 = 0, a2 = 0, a3 = 0, a4 = 0, a5 = 0, a6 = 0, a7 = 0;
  #pragma unroll 4
  for (int k = 0; k < 1024; k += 8) {
    a0 += hrow[k + 0] * wp[(size_t)(k + 0) * 512];
    a1 += hrow[k + 1] * wp[(size_t)(k + 1) * 512];
    a2 += hrow[k + 2] * wp[(size_t)(k + 2) * 512];
    a3 += hrow[k + 3] * wp[(size_t)(k + 3) * 512];
    a4 += hrow[k + 4] * wp[(size_t)(k + 4) * 512];
    a5 += hrow[k + 5] * wp[(size_t)(k + 5) * 512];
    a6 += hrow[k + 6] * wp[(size_t)(k + 6) * 512];
    a7 += hrow[k + 7] * wp[(size_t)(k + 7) * 512];
  }
  out[b * 512 + col] = ((a0 + a1) + (a2 + a3)) + ((a4 + a5) + (a6 + a7));
}

// ---------------- launch --------------------------------------------------
extern "C" void kernel_launch(void* const* d_in, const int* in_sizes, int n_in,
                              void* d_out, int out_size, void* d_ws, size_t ws_size,
                              hipStream_t stream) {
  const float* x    = (const float*)d_in[0];
  const float* Win  = (const float*)d_in[1];
  const float* bin  = (const float*)d_in[2];
  const float* Wh   = (const float*)d_in[3];
  const float* bh   = (const float*)d_in[4];
  const float* Wout = (const float*)d_in[5];
  const float* bout = (const float*)d_in[6];

  char* ws = (char*)d_ws;
  short* xin   = (short*)ws;                   // 67,108,864 B (re-laid-out)
  short* wprep = (short*)(ws + 67108864);      // 2 MB fragments
  short* hfrag = (short*)(ws + 69206016);      // 256 KB h fragments (2 parities)
  u32*   flags = (u32*)(ws + 69468160);        // 4*16 u32, padded to 1 KiB
  float* hfin  = (float*)(ws + 69469184);      // 256 KB

  hipMemsetAsync(flags, 0, 1024, stream);      // replay-deterministic
  hipLaunchKernelGGL(k_prep, dim3(64), dim3(256), 0, stream, Wh, wprep);
  hipLaunchKernelGGL(k_inproj, dim3(256, 8), dim3(256), 0, stream, x, Win, bin, xin);
  hipLaunchKernelGGL(k_recur, dim3(64), dim3(256), 0, stream,
                     xin, wprep, bh, hfrag, flags, hfin);
  hipLaunchKernelGGL(k_out, dim3(128), dim3(256), 0, stream, hfin, Wout, bout, (float*)d_out);
}